// Round 5
// baseline (948.524 us; speedup 1.0000x reference)
//
#include <hip/hip_runtime.h>

#define N_NODES 50000
#define N_EDGES 1600000
#define D 128
#define NCHUNK 196            // ceil(N_NODES/256) for scans
#define NBL 16384             // nodes per hist/fill block (64KB LDS)
#define NODEBLKS 4            // ceil(N_NODES/NBL)
#define NPAD (NODEBLKS*NBL)   // 65536
#define NSEG 32
#define CHUNKS_PER_SEG 12500  // uint4 chunks per segment (E/4/NSEG)
#define SLICES 4
#define SCOLS 32              // f16 cols per slice (64B)

typedef _Float16 f16x8 __attribute__((ext_vector_type(8)));
typedef float f32x4 __attribute__((ext_vector_type(4)));

union HU { uint4 u; f16x8 h; };
union U2 { uint2 u; _Float16 h[4]; };

// ---------------- preprocessing: node-range-owning scan (NO global atomics) ----------------

// Block (nb, s): stream segment s of col[], LDS-count hits among nodes [nb*NBL, nb*NBL+NBL).
__global__ __launch_bounds__(1024) void histA_kernel(const int* __restrict__ col, uint* __restrict__ C){
  __shared__ uint cnt[NBL];
  const int nb = blockIdx.x, s = blockIdx.y;
  const uint n0 = nb*NBL;
  const int t = threadIdx.x;
  #pragma unroll
  for (int k=0;k<NBL/1024;k++) cnt[k*1024 + t] = 0;
  __syncthreads();
  const uint4* cv = (const uint4*)col;
  const int cb = s*CHUNKS_PER_SEG, ce = cb + CHUNKS_PER_SEG;
  for (int c = cb + t; c < ce; c += 1024){
    uint4 v = cv[c];
    unsigned d0 = v.x - n0, d1 = v.y - n0, d2 = v.z - n0, d3 = v.w - n0;
    if (d0 < NBL) atomicAdd(&cnt[d0], 1u);
    if (d1 < NBL) atomicAdd(&cnt[d1], 1u);
    if (d2 < NBL) atomicAdd(&cnt[d2], 1u);
    if (d3 < NBL) atomicAdd(&cnt[d3], 1u);
  }
  __syncthreads();
  #pragma unroll
  for (int k=0;k<NBL/1024;k++)
    C[(size_t)s*NPAD + n0 + k*1024 + t] = cnt[k*1024 + t];
}

// In-place exclusive prefix of C along the segment axis; also deg & dinv.
__global__ __launch_bounds__(256) void segprefix_kernel(uint* __restrict__ C, int* __restrict__ deg,
                                                        float* __restrict__ dinv){
  int n = blockIdx.x*256 + threadIdx.x;
  if (n >= N_NODES) return;
  uint run = 0;
  #pragma unroll
  for (int s=0;s<NSEG;s++){
    uint v = C[(size_t)s*NPAD + n];
    C[(size_t)s*NPAD + n] = run;
    run += v;
  }
  deg[n] = (int)run;
  dinv[n] = (run > 0) ? rsqrtf((float)run) : 0.0f;
}

// ---------------- parallel exclusive scan (3 kernels) over deg -> off ----------------

__global__ __launch_bounds__(256) void scan1_kernel(const int* __restrict__ deg, int* __restrict__ chunkSum){
  __shared__ int red[256];
  int i = blockIdx.x*256 + threadIdx.x;
  red[threadIdx.x] = (i < N_NODES) ? deg[i] : 0;
  __syncthreads();
  for (int d=128; d>0; d>>=1){
    if (threadIdx.x < d) red[threadIdx.x] += red[threadIdx.x+d];
    __syncthreads();
  }
  if (threadIdx.x == 0) chunkSum[blockIdx.x] = red[0];
}

__global__ __launch_bounds__(256) void scan2_kernel(int* __restrict__ chunkSum, int* __restrict__ off){
  __shared__ int part[256];
  int t = threadIdx.x;
  int v = (t < NCHUNK) ? chunkSum[t] : 0;
  part[t] = v;
  __syncthreads();
  for (int d=1; d<256; d<<=1){
    int x = (t>=d) ? part[t-d] : 0;
    __syncthreads();
    part[t] += x;
    __syncthreads();
  }
  if (t < NCHUNK) chunkSum[t] = part[t] - v;   // exclusive chunk base
  if (t == 255) off[N_NODES] = part[255];
}

__global__ __launch_bounds__(256) void scan3_kernel(const int* __restrict__ deg, const int* __restrict__ chunkSum,
                                                    int* __restrict__ off){
  __shared__ int part[256];
  int t = threadIdx.x;
  int i = blockIdx.x*256 + t;
  int v = (i < N_NODES) ? deg[i] : 0;
  part[t] = v;
  __syncthreads();
  for (int d=1; d<256; d<<=1){
    int x = (t>=d) ? part[t-d] : 0;
    __syncthreads();
    part[t] += x;
    __syncthreads();
  }
  if (i < N_NODES) off[i] = chunkSum[blockIdx.x] + part[t] - v;
}

// ---------------- CSR fill: LDS cursors, exact per-(block,segment) bases, no global atomics ----------------
// Block (nb,s) writes only into a contiguous ~32KB window of csrS.

__global__ __launch_bounds__(1024) void fillB_kernel(const int* __restrict__ row, const int* __restrict__ col,
                                                     const int* __restrict__ off, const uint* __restrict__ C,
                                                     ushort* __restrict__ csrS){
  __shared__ uint cur[NBL];
  const int nb = blockIdx.x, s = blockIdx.y;
  const uint n0 = nb*NBL;
  const int t = threadIdx.x;
  #pragma unroll
  for (int k=0;k<NBL/1024;k++){
    int idx = k*1024 + t;
    int n = (int)n0 + idx;
    cur[idx] = (n < N_NODES) ? (uint)off[n] + C[(size_t)s*NPAD + n] : 0u;
  }
  __syncthreads();
  const uint4* cv = (const uint4*)col;
  const int cb = s*CHUNKS_PER_SEG, ce = cb + CHUNKS_PER_SEG;
  for (int c = cb + t; c < ce; c += 1024){
    uint4 v = cv[c];
    int e = c*4;
    unsigned d0 = v.x - n0, d1 = v.y - n0, d2 = v.z - n0, d3 = v.w - n0;
    if (d0 < NBL){ uint p = atomicAdd(&cur[d0], 1u); csrS[p] = (ushort)row[e+0]; }
    if (d1 < NBL){ uint p = atomicAdd(&cur[d1], 1u); csrS[p] = (ushort)row[e+1]; }
    if (d2 < NBL){ uint p = atomicAdd(&cur[d2], 1u); csrS[p] = (ushort)row[e+2]; }
    if (d3 < NBL){ uint p = atomicAdd(&cur[d3], 1u); csrS[p] = (ushort)row[e+3]; }
  }
}

// ---------------- fp32 -> f16 conversions ----------------

__global__ __launch_bounds__(256) void cvt_x_kernel(const float* __restrict__ x, const float* __restrict__ dinv,
                                                    ushort* __restrict__ x16, ushort* __restrict__ xs16){
  int i = blockIdx.x*256 + threadIdx.x;
  int node = i >> 4;
  float di = dinv[node];
  const float4* xin = (const float4*)x;
  float4 a = xin[(size_t)i*2], b = xin[(size_t)i*2+1];
  HU o, os;
  o.h[0]=(_Float16)a.x; o.h[1]=(_Float16)a.y; o.h[2]=(_Float16)a.z; o.h[3]=(_Float16)a.w;
  o.h[4]=(_Float16)b.x; o.h[5]=(_Float16)b.y; o.h[6]=(_Float16)b.z; o.h[7]=(_Float16)b.w;
  os.h[0]=(_Float16)(di*a.x); os.h[1]=(_Float16)(di*a.y); os.h[2]=(_Float16)(di*a.z); os.h[3]=(_Float16)(di*a.w);
  os.h[4]=(_Float16)(di*b.x); os.h[5]=(_Float16)(di*b.y); os.h[6]=(_Float16)(di*b.z); os.h[7]=(_Float16)(di*b.w);
  ((uint4*)x16)[i]  = o.u;
  ((uint4*)xs16)[i] = os.u;
}

__global__ __launch_bounds__(256) void cvt_w_kernel(const float* __restrict__ W1, const float* __restrict__ W2,
                                                    const float* __restrict__ W3, const float* __restrict__ Wf,
                                                    ushort* __restrict__ Wt){
  int m = blockIdx.x >> 2, q = blockIdx.x & 3;
  const float* src = (m < 4) ? (W1 + (size_t)m*16384)
                   : (m < 8) ? (W2 + (size_t)(m-4)*16384)
                   : (m < 12)? (W3 + (size_t)(m-8)*16384)
                   : Wf;
  ushort* dst = Wt + (size_t)m*16384;
  for (int it = threadIdx.x; it < 1024; it += 256){
    int idx = q*1024 + it;
    int n  = idx >> 5;
    int k4 = (idx & 31)*4;
    float v0 = src[(size_t)(k4+0)*D + n];
    float v1 = src[(size_t)(k4+1)*D + n];
    float v2 = src[(size_t)(k4+2)*D + n];
    float v3 = src[(size_t)(k4+3)*D + n];
    union { uint2 u; _Float16 h[4]; } o;
    o.h[0]=(_Float16)v0; o.h[1]=(_Float16)v1; o.h[2]=(_Float16)v2; o.h[3]=(_Float16)v3;
    *(uint2*)(dst + (size_t)n*D + k4) = o.u;
  }
}

// ---------------- SpMM, column-sliced (scaled-feature form) ----------------
// Slice = 32 f16 cols = one aligned 64B line per gathered row -> 3.2MB slice working set
// fits per-XCD L2. Grid (nodeblocks, 4 slices); x-fastest dispatch phases the machine
// slice-by-slice. 8 lanes/node, uint2 (4 f16) per lane, fp32 accumulate.
// out: hOut_i = dinv_i*acc_i ; sOut_i = dinv_i^2*acc_i (next hop's gather source).

template<bool WS>
__global__ __launch_bounds__(256) void spmm_slice_kernel(const ushort* __restrict__ sIn, ushort* __restrict__ hOut,
                                                         ushort* __restrict__ sOut,
                                                         const int* __restrict__ off, const ushort* __restrict__ csrS,
                                                         const float* __restrict__ dinv){
  const int t = threadIdx.x;
  const int node = blockIdx.x*32 + (t >> 3);
  if (node >= N_NODES) return;
  const int cbase = blockIdx.y*SCOLS + (t & 7)*4;
  const int b = off[node], e = off[node+1];
  float a0=0.f, a1=0.f, a2=0.f, a3=0.f;
  int i = b;
  for (; i+4 <= e; i += 4){
    int s0 = csrS[i], s1 = csrS[i+1], s2 = csrS[i+2], s3 = csrS[i+3];
    U2 v0, v1, v2, v3;
    v0.u = *(const uint2*)(sIn + (size_t)s0*D + cbase);
    v1.u = *(const uint2*)(sIn + (size_t)s1*D + cbase);
    v2.u = *(const uint2*)(sIn + (size_t)s2*D + cbase);
    v3.u = *(const uint2*)(sIn + (size_t)s3*D + cbase);
    a0 += ((float)v0.h[0] + (float)v1.h[0]) + ((float)v2.h[0] + (float)v3.h[0]);
    a1 += ((float)v0.h[1] + (float)v1.h[1]) + ((float)v2.h[1] + (float)v3.h[1]);
    a2 += ((float)v0.h[2] + (float)v1.h[2]) + ((float)v2.h[2] + (float)v3.h[2]);
    a3 += ((float)v0.h[3] + (float)v1.h[3]) + ((float)v2.h[3] + (float)v3.h[3]);
  }
  for (; i < e; i++){
    int s0 = csrS[i];
    U2 v0; v0.u = *(const uint2*)(sIn + (size_t)s0*D + cbase);
    a0 += (float)v0.h[0]; a1 += (float)v0.h[1]; a2 += (float)v0.h[2]; a3 += (float)v0.h[3];
  }
  float di = dinv[node];
  U2 oh;
  float h0 = di*a0, h1 = di*a1, h2 = di*a2, h3 = di*a3;
  oh.h[0]=(_Float16)h0; oh.h[1]=(_Float16)h1; oh.h[2]=(_Float16)h2; oh.h[3]=(_Float16)h3;
  *(uint2*)(hOut + (size_t)node*D + cbase) = oh.u;
  if (WS){
    U2 os;
    os.h[0]=(_Float16)(di*h0); os.h[1]=(_Float16)(di*h1);
    os.h[2]=(_Float16)(di*h2); os.h[3]=(_Float16)(di*h3);
    *(uint2*)(sOut + (size_t)node*D + cbase) = os.u;
  }
}

// ---------------- fused layer GEMM via MFMA f16 ----------------
// out = relu( sum_src S_src @ W_src + b ); optionally also sOut = dinv.*out.
// NOTE: out may alias s0 — each block reads exactly the rows it writes (staging), stores after.

template<int NSRC, bool RELU, bool OUTF32, bool WS>
__global__ __launch_bounds__(256) void gemm_mfma_kernel(const ushort* s0,
    const ushort* __restrict__ s1, const ushort* __restrict__ s2, const ushort* __restrict__ s3,
    const ushort* __restrict__ Wt, const float* __restrict__ bias, const float* __restrict__ dinv,
    void* outp, ushort* __restrict__ sOut){
  __shared__ ushort Xs[64*136];
  const int tid  = threadIdx.x;
  const int wave = tid >> 6, lane = tid & 63;
  const int quad = lane >> 4, l16 = lane & 15;
  const int wm = wave & 1, wn = wave >> 1;
  const int row0 = blockIdx.x * 64;

  f32x4 acc[2][4];
  #pragma unroll
  for (int i=0;i<2;i++)
    #pragma unroll
    for (int j=0;j<4;j++) acc[i][j] = (f32x4){0.f,0.f,0.f,0.f};

  #pragma unroll
  for (int src=0; src<NSRC; src++){
    const ushort* sp = (src==0)?s0:(src==1)?s1:(src==2)?s2:s3;
    __syncthreads();
    for (int i=tid; i<1024; i+=256){
      int r = i >> 4, c = i & 15;
      int gr = row0 + r;
      uint4 v = make_uint4(0u,0u,0u,0u);
      if (gr < N_NODES) v = *(const uint4*)(sp + (size_t)gr*D + c*8);
      *(uint4*)(&Xs[r*136 + c*8]) = v;
    }
    __syncthreads();
    const ushort* wsrc = Wt + (size_t)src*16384;
    #pragma unroll
    for (int ks=0; ks<4; ks++){
      f16x8 a0 = *(const f16x8*)(&Xs[(wm*32 +      l16)*136 + ks*32 + quad*8]);
      f16x8 a1 = *(const f16x8*)(&Xs[(wm*32 + 16 + l16)*136 + ks*32 + quad*8]);
      #pragma unroll
      for (int j=0;j<4;j++){
        f16x8 b = *(const f16x8*)(wsrc + (size_t)(wn*64 + j*16 + l16)*D + ks*32 + quad*8);
        acc[0][j] = __builtin_amdgcn_mfma_f32_16x16x32_f16(a0, b, acc[0][j], 0, 0, 0);
        acc[1][j] = __builtin_amdgcn_mfma_f32_16x16x32_f16(a1, b, acc[1][j], 0, 0, 0);
      }
    }
  }
  #pragma unroll
  for (int j=0;j<4;j++){
    int colj = wn*64 + j*16 + l16;
    float bv = bias[colj];
    #pragma unroll
    for (int i=0;i<2;i++){
      int brow = row0 + wm*32 + i*16 + quad*4;
      #pragma unroll
      for (int r=0;r<4;r++){
        int grow = brow + r;
        if (grow < N_NODES){
          float v = acc[i][j][r] + bv;
          if (RELU) v = fmaxf(v, 0.f);
          if (OUTF32){
            ((float*)outp)[(size_t)grow*D + colj] = v;
          } else {
            ((ushort*)outp)[(size_t)grow*D + colj] = __builtin_bit_cast(ushort, (_Float16)v);
            if (WS) sOut[(size_t)grow*D + colj] = __builtin_bit_cast(ushort, (_Float16)(dinv[grow]*v));
          }
        }
      }
    }
  }
}

// ---------------- launch ----------------

extern "C" void kernel_launch(void* const* d_in, const int* in_sizes, int n_in,
                              void* d_out, int out_size, void* d_ws, size_t ws_size,
                              hipStream_t stream){
  const float* x  = (const float*)d_in[0];
  const int*   ei = (const int*)d_in[1];
  const float* W1 = (const float*)d_in[2];
  const float* b1 = (const float*)d_in[3];
  const float* W2 = (const float*)d_in[4];
  const float* b2 = (const float*)d_in[5];
  const float* W3 = (const float*)d_in[6];
  const float* b3 = (const float*)d_in[7];
  const float* Wf = (const float*)d_in[8];
  const float* bf = (const float*)d_in[9];
  float* out = (float*)d_out;

  const int* row = ei;            // edge_index[0]
  const int* col = ei + N_EDGES;  // edge_index[1]

  // workspace layout
  char* w = (char*)d_ws;
  ushort* csrS = (ushort*)w;  w += (size_t)N_EDGES*2;
  ushort* x16  = (ushort*)w;  w += (size_t)N_NODES*D*2;
  ushort* xs16 = (ushort*)w;  w += (size_t)N_NODES*D*2;    // reused as Dh after hop-1 (dead then)
  ushort* Ah   = (ushort*)w;  w += (size_t)N_NODES*D*2;
  ushort* As   = (ushort*)w;  w += (size_t)N_NODES*D*2;
  ushort* Bh   = (ushort*)w;  w += (size_t)N_NODES*D*2;
  ushort* Bs   = (ushort*)w;  w += (size_t)N_NODES*D*2;
  ushort* Ch   = (ushort*)w;  w += (size_t)N_NODES*D*2;
  ushort* Cs   = (ushort*)w;  w += (size_t)N_NODES*D*2;
  ushort* Wt   = (ushort*)w;  w += (size_t)13*D*D*2;
  uint* Cc     = (uint*)w;    w += (size_t)NSEG*NPAD*4;    // per-(segment,node) exclusive counts
  int* deg     = (int*)w;     w += (size_t)N_NODES*4;
  int* off     = (int*)w;     w += (size_t)(N_NODES+1)*4;
  int* chunkS  = (int*)w;     w += (size_t)256*4;
  float* dinv  = (float*)w;
  ushort* Dh = xs16;

  const int GB = (N_NODES + 63)/64;            // 782
  const dim3 SG((N_NODES + 31)/32, SLICES);    // (1563, 4)

  histA_kernel<<<dim3(NODEBLKS,NSEG),1024,0,stream>>>(col, Cc);
  segprefix_kernel<<<NCHUNK,256,0,stream>>>(Cc, deg, dinv);
  scan1_kernel<<<NCHUNK,256,0,stream>>>(deg, chunkS);
  scan2_kernel<<<1,256,0,stream>>>(chunkS, off);
  scan3_kernel<<<NCHUNK,256,0,stream>>>(deg, chunkS, off);
  fillB_kernel<<<dim3(NODEBLKS,NSEG),1024,0,stream>>>(row, col, off, Cc, csrS);
  cvt_x_kernel<<<3125,256,0,stream>>>(x, dinv, x16, xs16);
  cvt_w_kernel<<<52,256,0,stream>>>(W1, W2, W3, Wf, Wt);

  // layer 1
  spmm_slice_kernel<true ><<<SG,256,0,stream>>>(xs16, Bh, Bs, off, csrS, dinv);
  spmm_slice_kernel<true ><<<SG,256,0,stream>>>(Bs,   Ch, Cs, off, csrS, dinv);
  spmm_slice_kernel<false><<<SG,256,0,stream>>>(Cs,   Dh, nullptr, off, csrS, dinv);
  gemm_mfma_kernel<4,true,false,true><<<GB,256,0,stream>>>(x16, Bh, Ch, Dh, Wt+0*16384, b1, dinv, Ah, As);
  // layer 2 (gemm out aliases its s0 = Ah; safe)
  spmm_slice_kernel<true ><<<SG,256,0,stream>>>(As, Bh, Bs, off, csrS, dinv);
  spmm_slice_kernel<true ><<<SG,256,0,stream>>>(Bs, Ch, Cs, off, csrS, dinv);
  spmm_slice_kernel<false><<<SG,256,0,stream>>>(Cs, Dh, nullptr, off, csrS, dinv);
  gemm_mfma_kernel<4,true,false,true><<<GB,256,0,stream>>>(Ah, Bh, Ch, Dh, Wt+4*16384, b2, dinv, Ah, As);
  // layer 3
  spmm_slice_kernel<true ><<<SG,256,0,stream>>>(As, Bh, Bs, off, csrS, dinv);
  spmm_slice_kernel<true ><<<SG,256,0,stream>>>(Bs, Ch, Cs, off, csrS, dinv);
  spmm_slice_kernel<false><<<SG,256,0,stream>>>(Cs, Dh, nullptr, off, csrS, dinv);
  gemm_mfma_kernel<4,true,false,true><<<GB,256,0,stream>>>(Ah, Bh, Ch, Dh, Wt+8*16384, b3, dinv, Ah, As);
  // final head (fp32 out)
  gemm_mfma_kernel<1,false,true,false><<<GB,256,0,stream>>>(Ah, nullptr, nullptr, nullptr, Wt+12*16384, bf, dinv, out, nullptr);
}

// Round 6
// 863.100 us; speedup vs baseline: 1.0990x; 1.0990x over previous
//
#include <hip/hip_runtime.h>

#define N_NODES 50000
#define N_EDGES 1600000
#define D 128
#define NS 1600000            // slab stride in ushorts (N_NODES*32)
#define NCHUNK 196            // ceil(N_NODES/256) for scans
#define NBL 1024              // nodes per hist/fill block
#define NODEBLKS 49           // ceil(N_NODES/NBL)
#define NPAD (NODEBLKS*NBL)   // 50176
#define NSEG 8
#define CHUNKS_PER_SEG 50000  // uint4 chunks per segment (E/4/NSEG)

typedef _Float16 f16x8 __attribute__((ext_vector_type(8)));
typedef float f32x4 __attribute__((ext_vector_type(4)));
typedef uint u32x4 __attribute__((ext_vector_type(4)));

union HU { uint4 u; f16x8 h; };
union HV { u32x4 u; _Float16 h[8]; };

// ---------------- preprocessing: node-range-owning scan (NO global atomics) ----------------

__global__ __launch_bounds__(1024) void histA_kernel(const int* __restrict__ col, uint* __restrict__ C){
  __shared__ uint cnt[NBL];
  const int nb = blockIdx.x, s = blockIdx.y;
  const uint n0 = nb*NBL;
  const int t = threadIdx.x;
  cnt[t] = 0;
  __syncthreads();
  const uint4* cv = (const uint4*)col;
  const int cb = s*CHUNKS_PER_SEG, ce = cb + CHUNKS_PER_SEG;
  for (int c = cb + t; c < ce; c += 1024){
    uint4 v = cv[c];
    unsigned d0 = v.x - n0, d1 = v.y - n0, d2 = v.z - n0, d3 = v.w - n0;
    if (d0 < NBL) atomicAdd(&cnt[d0], 1u);
    if (d1 < NBL) atomicAdd(&cnt[d1], 1u);
    if (d2 < NBL) atomicAdd(&cnt[d2], 1u);
    if (d3 < NBL) atomicAdd(&cnt[d3], 1u);
  }
  __syncthreads();
  C[(size_t)s*NPAD + n0 + t] = cnt[t];
}

// In-place exclusive prefix of C along the segment axis; also deg & dinv.
__global__ __launch_bounds__(256) void segprefix_kernel(uint* __restrict__ C, int* __restrict__ deg,
                                                        float* __restrict__ dinv){
  int n = blockIdx.x*256 + threadIdx.x;
  if (n >= N_NODES) return;
  uint run = 0;
  #pragma unroll
  for (int s=0;s<NSEG;s++){
    uint v = C[(size_t)s*NPAD + n];
    C[(size_t)s*NPAD + n] = run;
    run += v;
  }
  deg[n] = (int)run;
  dinv[n] = (run > 0) ? rsqrtf((float)run) : 0.0f;
}

// ---------------- parallel exclusive scan (3 kernels) over deg -> off ----------------

__global__ __launch_bounds__(256) void scan1_kernel(const int* __restrict__ deg, int* __restrict__ chunkSum){
  __shared__ int red[256];
  int i = blockIdx.x*256 + threadIdx.x;
  red[threadIdx.x] = (i < N_NODES) ? deg[i] : 0;
  __syncthreads();
  for (int d=128; d>0; d>>=1){
    if (threadIdx.x < d) red[threadIdx.x] += red[threadIdx.x+d];
    __syncthreads();
  }
  if (threadIdx.x == 0) chunkSum[blockIdx.x] = red[0];
}

__global__ __launch_bounds__(256) void scan2_kernel(int* __restrict__ chunkSum, int* __restrict__ off){
  __shared__ int part[256];
  int t = threadIdx.x;
  int v = (t < NCHUNK) ? chunkSum[t] : 0;
  part[t] = v;
  __syncthreads();
  for (int d=1; d<256; d<<=1){
    int x = (t>=d) ? part[t-d] : 0;
    __syncthreads();
    part[t] += x;
    __syncthreads();
  }
  if (t < NCHUNK) chunkSum[t] = part[t] - v;   // exclusive chunk base
  if (t == 255) off[N_NODES] = part[255];
}

__global__ __launch_bounds__(256) void scan3_kernel(const int* __restrict__ deg, const int* __restrict__ chunkSum,
                                                    int* __restrict__ off){
  __shared__ int part[256];
  int t = threadIdx.x;
  int i = blockIdx.x*256 + t;
  int v = (i < N_NODES) ? deg[i] : 0;
  part[t] = v;
  __syncthreads();
  for (int d=1; d<256; d<<=1){
    int x = (t>=d) ? part[t-d] : 0;
    __syncthreads();
    part[t] += x;
    __syncthreads();
  }
  if (i < N_NODES) off[i] = chunkSum[blockIdx.x] + part[t] - v;
}

// ---------------- CSR fill: LDS cursors, exact per-(block,segment) bases, no global atomics ----------------
// row streamed unconditionally (coalesced uint4) alongside col — no sparse line fetches.

__global__ __launch_bounds__(1024) void fillB_kernel(const int* __restrict__ row, const int* __restrict__ col,
                                                     const int* __restrict__ off, const uint* __restrict__ C,
                                                     ushort* __restrict__ csrS){
  __shared__ uint cur[NBL];
  const int nb = blockIdx.x, s = blockIdx.y;
  const uint n0 = nb*NBL;
  const int t = threadIdx.x;
  {
    int n = (int)n0 + t;
    cur[t] = (n < N_NODES) ? (uint)off[n] + C[(size_t)s*NPAD + n] : 0u;
  }
  __syncthreads();
  const uint4* cvv = (const uint4*)col;
  const uint4* rvv = (const uint4*)row;
  const int cb = s*CHUNKS_PER_SEG, ce = cb + CHUNKS_PER_SEG;
  for (int c = cb + t; c < ce; c += 1024){
    uint4 cv4 = cvv[c];
    uint4 rv4 = rvv[c];
    unsigned d0 = cv4.x - n0, d1 = cv4.y - n0, d2 = cv4.z - n0, d3 = cv4.w - n0;
    if (d0 < NBL){ uint p = atomicAdd(&cur[d0], 1u); csrS[p] = (ushort)rv4.x; }
    if (d1 < NBL){ uint p = atomicAdd(&cur[d1], 1u); csrS[p] = (ushort)rv4.y; }
    if (d2 < NBL){ uint p = atomicAdd(&cur[d2], 1u); csrS[p] = (ushort)rv4.z; }
    if (d3 < NBL){ uint p = atomicAdd(&cur[d3], 1u); csrS[p] = (ushort)rv4.w; }
  }
}

// ---------------- fp32 -> f16 conversions (slab-major feature layout) ----------------
// Feature buffers: 4 slabs of N_NODES x 32 f16; element (node, col) at slab(col>>5)*NS + node*32 + (col&31).

__global__ __launch_bounds__(256) void cvt_x_kernel(const float* __restrict__ x, const float* __restrict__ dinv,
                                                    ushort* __restrict__ x16, ushort* __restrict__ xs16){
  int i = blockIdx.x*256 + threadIdx.x;   // 800000 chunks of 8 f16
  int node = i >> 4, cc = i & 15;
  float di = dinv[node];
  const float4* xin = (const float4*)x;
  float4 a = xin[(size_t)i*2], b = xin[(size_t)i*2+1];
  HU o, os;
  o.h[0]=(_Float16)a.x; o.h[1]=(_Float16)a.y; o.h[2]=(_Float16)a.z; o.h[3]=(_Float16)a.w;
  o.h[4]=(_Float16)b.x; o.h[5]=(_Float16)b.y; o.h[6]=(_Float16)b.z; o.h[7]=(_Float16)b.w;
  os.h[0]=(_Float16)(di*a.x); os.h[1]=(_Float16)(di*a.y); os.h[2]=(_Float16)(di*a.z); os.h[3]=(_Float16)(di*a.w);
  os.h[4]=(_Float16)(di*b.x); os.h[5]=(_Float16)(di*b.y); os.h[6]=(_Float16)(di*b.z); os.h[7]=(_Float16)(di*b.w);
  size_t dst = (size_t)(cc>>2)*NS + (size_t)node*32 + (cc&3)*8;
  *(uint4*)(x16 + dst)  = o.u;
  *(uint4*)(xs16 + dst) = os.u;
}

__global__ __launch_bounds__(256) void cvt_w_kernel(const float* __restrict__ W1, const float* __restrict__ W2,
                                                    const float* __restrict__ W3, const float* __restrict__ Wf,
                                                    ushort* __restrict__ Wt){
  int m = blockIdx.x >> 2, q = blockIdx.x & 3;
  const float* src = (m < 4) ? (W1 + (size_t)m*16384)
                   : (m < 8) ? (W2 + (size_t)(m-4)*16384)
                   : (m < 12)? (W3 + (size_t)(m-8)*16384)
                   : Wf;
  ushort* dst = Wt + (size_t)m*16384;
  for (int it = threadIdx.x; it < 1024; it += 256){
    int idx = q*1024 + it;
    int n  = idx >> 5;
    int k4 = (idx & 31)*4;
    float v0 = src[(size_t)(k4+0)*D + n];
    float v1 = src[(size_t)(k4+1)*D + n];
    float v2 = src[(size_t)(k4+2)*D + n];
    float v3 = src[(size_t)(k4+3)*D + n];
    union { uint2 u; _Float16 h[4]; } o;
    o.h[0]=(_Float16)v0; o.h[1]=(_Float16)v1; o.h[2]=(_Float16)v2; o.h[3]=(_Float16)v3;
    *(uint2*)(dst + (size_t)n*D + k4) = o.u;
  }
}

// ---------------- SpMM over one 3.2MB slab (launched once per slice -> hard phase barrier) ----------------
// 16 lanes/node: quad q handles edges b+q, b+q+4, ... (x2 unrolled); each quad's uint4 = full 64B
// slice-row of the source node. Cross-quad shfl_xor reduce; q==0 lanes store (nontemporal).

template<bool WS>
__global__ __launch_bounds__(256) void spmm_slab_kernel(const ushort* __restrict__ sIn,
                                                        ushort* __restrict__ hOut, ushort* __restrict__ sOut,
                                                        const int* __restrict__ off, const ushort* __restrict__ csrS,
                                                        const float* __restrict__ dinv){
  const int t = threadIdx.x;
  const int node = blockIdx.x*16 + (t >> 4);   // grid 3125 x 16 nodes = 50000 exact
  const int ln = t & 15, q = ln >> 2, c = ln & 3;
  const int b = off[node], e = off[node+1];
  float acc[8];
  #pragma unroll
  for (int k=0;k<8;k++) acc[k] = 0.f;
  int i = b + q;
  for (; i + 4 < e; i += 8){
    int s0 = csrS[i], s1 = csrS[i+4];
    HV v0, v1;
    v0.u = *(const u32x4*)(sIn + (size_t)s0*32 + c*8);
    v1.u = *(const u32x4*)(sIn + (size_t)s1*32 + c*8);
    #pragma unroll
    for (int k=0;k<8;k++) acc[k] += (float)v0.h[k] + (float)v1.h[k];
  }
  if (i < e){
    int s0 = csrS[i];
    HV v0;
    v0.u = *(const u32x4*)(sIn + (size_t)s0*32 + c*8);
    #pragma unroll
    for (int k=0;k<8;k++) acc[k] += (float)v0.h[k];
  }
  // reduce across quads (lanes xor 4, 8 stay inside the 16-lane node group)
  #pragma unroll
  for (int k=0;k<8;k++){
    acc[k] += __shfl_xor(acc[k], 4, 64);
    acc[k] += __shfl_xor(acc[k], 8, 64);
  }
  if (q == 0){
    float di = dinv[node];
    HV oh;
    #pragma unroll
    for (int k=0;k<8;k++) oh.h[k] = (_Float16)(di*acc[k]);
    __builtin_nontemporal_store(oh.u, (u32x4*)(hOut + (size_t)node*32 + c*8));
    if (WS){
      HV os;
      #pragma unroll
      for (int k=0;k<8;k++) os.h[k] = (_Float16)(di*di*acc[k]);
      __builtin_nontemporal_store(os.u, (u32x4*)(sOut + (size_t)node*32 + c*8));
    }
  }
}

// ---------------- fused layer GEMM via MFMA f16 (slab-layout inputs/outputs) ----------------
// out = relu( sum_src S_src @ W_src + b ); optionally also sOut = dinv.*out.
// NOTE: out may alias s0 — each block reads exactly the rows it writes (staging), stores after.

template<int NSRC, bool RELU, bool OUTF32, bool WS>
__global__ __launch_bounds__(256) void gemm_mfma_kernel(const ushort* s0,
    const ushort* __restrict__ s1, const ushort* __restrict__ s2, const ushort* __restrict__ s3,
    const ushort* __restrict__ Wt, const float* __restrict__ bias, const float* __restrict__ dinv,
    void* outp, ushort* __restrict__ sOut){
  __shared__ ushort Xs[64*136];
  const int tid  = threadIdx.x;
  const int wave = tid >> 6, lane = tid & 63;
  const int quad = lane >> 4, l16 = lane & 15;
  const int wm = wave & 1, wn = wave >> 1;
  const int row0 = blockIdx.x * 64;

  f32x4 acc[2][4];
  #pragma unroll
  for (int i=0;i<2;i++)
    #pragma unroll
    for (int j=0;j<4;j++) acc[i][j] = (f32x4){0.f,0.f,0.f,0.f};

  #pragma unroll
  for (int src=0; src<NSRC; src++){
    const ushort* sp = (src==0)?s0:(src==1)?s1:(src==2)?s2:s3;
    __syncthreads();
    for (int i=tid; i<1024; i+=256){
      int r = i >> 4, cc = i & 15;
      int gr = row0 + r;
      uint4 v = make_uint4(0u,0u,0u,0u);
      if (gr < N_NODES) v = *(const uint4*)(sp + (size_t)(cc>>2)*NS + (size_t)gr*32 + (cc&3)*8);
      *(uint4*)(&Xs[r*136 + cc*8]) = v;
    }
    __syncthreads();
    const ushort* wsrc = Wt + (size_t)src*16384;
    #pragma unroll
    for (int ks=0; ks<4; ks++){
      f16x8 a0 = *(const f16x8*)(&Xs[(wm*32 +      l16)*136 + ks*32 + quad*8]);
      f16x8 a1 = *(const f16x8*)(&Xs[(wm*32 + 16 + l16)*136 + ks*32 + quad*8]);
      #pragma unroll
      for (int j=0;j<4;j++){
        f16x8 bfrag = *(const f16x8*)(wsrc + (size_t)(wn*64 + j*16 + l16)*D + ks*32 + quad*8);
        acc[0][j] = __builtin_amdgcn_mfma_f32_16x16x32_f16(a0, bfrag, acc[0][j], 0, 0, 0);
        acc[1][j] = __builtin_amdgcn_mfma_f32_16x16x32_f16(a1, bfrag, acc[1][j], 0, 0, 0);
      }
    }
  }
  #pragma unroll
  for (int j=0;j<4;j++){
    int colj = wn*64 + j*16 + l16;
    float bv = bias[colj];
    int slab = colj >> 5, cw = colj & 31;
    #pragma unroll
    for (int i=0;i<2;i++){
      int brow = row0 + wm*32 + i*16 + quad*4;
      #pragma unroll
      for (int r=0;r<4;r++){
        int grow = brow + r;
        if (grow < N_NODES){
          float v = acc[i][j][r] + bv;
          if (RELU) v = fmaxf(v, 0.f);
          if (OUTF32){
            ((float*)outp)[(size_t)grow*D + colj] = v;
          } else {
            size_t dst = (size_t)slab*NS + (size_t)grow*32 + cw;
            ((ushort*)outp)[dst] = __builtin_bit_cast(ushort, (_Float16)v);
            if (WS) sOut[dst] = __builtin_bit_cast(ushort, (_Float16)(dinv[grow]*v));
          }
        }
      }
    }
  }
}

// ---------------- launch ----------------

extern "C" void kernel_launch(void* const* d_in, const int* in_sizes, int n_in,
                              void* d_out, int out_size, void* d_ws, size_t ws_size,
                              hipStream_t stream){
  const float* x  = (const float*)d_in[0];
  const int*   ei = (const int*)d_in[1];
  const float* W1 = (const float*)d_in[2];
  const float* b1 = (const float*)d_in[3];
  const float* W2 = (const float*)d_in[4];
  const float* b2 = (const float*)d_in[5];
  const float* W3 = (const float*)d_in[6];
  const float* b3 = (const float*)d_in[7];
  const float* Wf = (const float*)d_in[8];
  const float* bf = (const float*)d_in[9];
  float* out = (float*)d_out;

  const int* row = ei;            // edge_index[0]
  const int* col = ei + N_EDGES;  // edge_index[1]

  // workspace layout (~109 MB)
  char* w = (char*)d_ws;
  ushort* csrS = (ushort*)w;  w += (size_t)N_EDGES*2;
  ushort* x16  = (ushort*)w;  w += (size_t)N_NODES*D*2;
  ushort* xs16 = (ushort*)w;  w += (size_t)N_NODES*D*2;    // reused as Dh after hop-1 (dead then)
  ushort* Ah   = (ushort*)w;  w += (size_t)N_NODES*D*2;
  ushort* As   = (ushort*)w;  w += (size_t)N_NODES*D*2;
  ushort* Bh   = (ushort*)w;  w += (size_t)N_NODES*D*2;
  ushort* Bs   = (ushort*)w;  w += (size_t)N_NODES*D*2;
  ushort* Ch   = (ushort*)w;  w += (size_t)N_NODES*D*2;
  ushort* Cs   = (ushort*)w;  w += (size_t)N_NODES*D*2;
  ushort* Wt   = (ushort*)w;  w += (size_t)13*D*D*2;
  uint* Cc     = (uint*)w;    w += (size_t)NSEG*NPAD*4;    // per-(segment,node) exclusive counts
  int* deg     = (int*)w;     w += (size_t)N_NODES*4;
  int* off     = (int*)w;     w += (size_t)(N_NODES+1)*4;
  int* chunkS  = (int*)w;     w += (size_t)256*4;
  float* dinv  = (float*)w;
  ushort* Dh = xs16;

  const int GB = (N_NODES + 63)/64;   // 782
  const int SB = N_NODES/16;          // 3125 (exact)

  histA_kernel<<<dim3(NODEBLKS,NSEG),1024,0,stream>>>(col, Cc);
  segprefix_kernel<<<NCHUNK,256,0,stream>>>(Cc, deg, dinv);
  scan1_kernel<<<NCHUNK,256,0,stream>>>(deg, chunkS);
  scan2_kernel<<<1,256,0,stream>>>(chunkS, off);
  scan3_kernel<<<NCHUNK,256,0,stream>>>(deg, chunkS, off);
  fillB_kernel<<<dim3(NODEBLKS,NSEG),1024,0,stream>>>(row, col, off, Cc, csrS);
  cvt_x_kernel<<<3125,256,0,stream>>>(x, dinv, x16, xs16);
  cvt_w_kernel<<<52,256,0,stream>>>(W1, W2, W3, Wf, Wt);

  // one launch per (hop, slice): the dispatch boundary IS the phase barrier
  #define HOP(IN, HO, SO) \
    for (int s = 0; s < 4; s++) \
      spmm_slab_kernel<true ><<<SB,256,0,stream>>>((IN)+(size_t)s*NS, (HO)+(size_t)s*NS, (SO)+(size_t)s*NS, off, csrS, dinv);
  #define HOPN(IN, HO) \
    for (int s = 0; s < 4; s++) \
      spmm_slab_kernel<false><<<SB,256,0,stream>>>((IN)+(size_t)s*NS, (HO)+(size_t)s*NS, nullptr, off, csrS, dinv);

  // layer 1
  HOP (xs16, Bh, Bs)
  HOP (Bs,   Ch, Cs)
  HOPN(Cs,   Dh)
  gemm_mfma_kernel<4,true,false,true><<<GB,256,0,stream>>>(x16, Bh, Ch, Dh, Wt+0*16384, b1, dinv, Ah, As);
  // layer 2 (gemm out aliases its s0 = Ah; safe)
  HOP (As, Bh, Bs)
  HOP (Bs, Ch, Cs)
  HOPN(Cs, Dh)
  gemm_mfma_kernel<4,true,false,true><<<GB,256,0,stream>>>(Ah, Bh, Ch, Dh, Wt+4*16384, b2, dinv, Ah, As);
  // layer 3
  HOP (As, Bh, Bs)
  HOP (Bs, Ch, Cs)
  HOPN(Cs, Dh)
  gemm_mfma_kernel<4,true,false,true><<<GB,256,0,stream>>>(Ah, Bh, Ch, Dh, Wt+8*16384, b3, dinv, Ah, As);
  // final head (fp32 row-major out)
  gemm_mfma_kernel<1,false,true,false><<<GB,256,0,stream>>>(Ah, nullptr, nullptr, nullptr, Wt+12*16384, bf, dinv, out, nullptr);
  #undef HOP
  #undef HOPN
}

// Round 9
// 745.472 us; speedup vs baseline: 1.2724x; 1.1578x over previous
//
#include <hip/hip_runtime.h>

#define N_NODES 50000
#define N_EDGES 1600000
#define D 128
#define NCHUNK 196            // ceil(N_NODES/256) for scans
#define NBL 16384             // nodes per hist/fill block (64KB LDS; 1024-thr blocks cap at 2/CU anyway)
#define NODEBLKS 4            // ceil(N_NODES/NBL)
#define NPAD 65536            // NODEBLKS*NBL
#define NSEG 128
#define CHUNKS_PER_SEG 3125   // uint4 chunks per segment (E/4/NSEG)

typedef _Float16 f16x8 __attribute__((ext_vector_type(8)));
typedef float f32x4 __attribute__((ext_vector_type(4)));
typedef uint u32x4 __attribute__((ext_vector_type(4)));   // ext-vector: valid for nontemporal builtins

union HU { uint4 u; u32x4 v; _Float16 h[8]; };

// ---------------- preprocessing: node-range-owning scan (NO global atomics) ----------------
// Block (nb,s): stream segment s of col[], LDS-count hits among its 16384 nodes.
// col re-read = NODEBLKS x (25.6MB total) vs 49x in the round-4 geometry.

__global__ __launch_bounds__(1024) void histA_kernel(const int* __restrict__ col, ushort* __restrict__ C){
  __shared__ uint cnt[NBL];
  const int nb = blockIdx.x, s = blockIdx.y;
  const uint n0 = nb*NBL;
  const int t = threadIdx.x;
  #pragma unroll
  for (int k=0;k<NBL/1024;k++) cnt[k*1024 + t] = 0;
  __syncthreads();
  const uint4* cv = (const uint4*)col;
  const int cb = s*CHUNKS_PER_SEG, ce = cb + CHUNKS_PER_SEG;
  for (int c = cb + t; c < ce; c += 1024){
    uint4 v = cv[c];
    unsigned d0 = v.x - n0, d1 = v.y - n0, d2 = v.z - n0, d3 = v.w - n0;
    if (d0 < NBL) atomicAdd(&cnt[d0], 1u);
    if (d1 < NBL) atomicAdd(&cnt[d1], 1u);
    if (d2 < NBL) atomicAdd(&cnt[d2], 1u);
    if (d3 < NBL) atomicAdd(&cnt[d3], 1u);
  }
  __syncthreads();
  #pragma unroll
  for (int k=0;k<NBL/1024;k++)
    C[(size_t)s*NPAD + n0 + k*1024 + t] = (ushort)cnt[k*1024 + t];
}

// In-place exclusive prefix of C along the segment axis (ushort: per-segment count <= 12500); also deg & dinv.
__global__ __launch_bounds__(256) void segprefix_kernel(ushort* __restrict__ C, int* __restrict__ deg,
                                                        float* __restrict__ dinv){
  int n = blockIdx.x*256 + threadIdx.x;
  if (n >= N_NODES) return;
  uint run = 0;
  #pragma unroll
  for (int s=0;s<NSEG;s++){
    uint v = C[(size_t)s*NPAD + n];
    C[(size_t)s*NPAD + n] = (ushort)run;
    run += v;
  }
  deg[n] = (int)run;
  dinv[n] = (run > 0) ? rsqrtf((float)run) : 0.0f;
}

// ---------------- parallel exclusive scan (3 kernels) over deg -> off ----------------

__global__ __launch_bounds__(256) void scan1_kernel(const int* __restrict__ deg, int* __restrict__ chunkSum){
  __shared__ int red[256];
  int i = blockIdx.x*256 + threadIdx.x;
  red[threadIdx.x] = (i < N_NODES) ? deg[i] : 0;
  __syncthreads();
  for (int d=128; d>0; d>>=1){
    if (threadIdx.x < d) red[threadIdx.x] += red[threadIdx.x+d];
    __syncthreads();
  }
  if (threadIdx.x == 0) chunkSum[blockIdx.x] = red[0];
}

__global__ __launch_bounds__(256) void scan2_kernel(int* __restrict__ chunkSum, int* __restrict__ off){
  __shared__ int part[256];
  int t = threadIdx.x;
  int v = (t < NCHUNK) ? chunkSum[t] : 0;
  part[t] = v;
  __syncthreads();
  for (int d=1; d<256; d<<=1){
    int x = (t>=d) ? part[t-d] : 0;
    __syncthreads();
    part[t] += x;
    __syncthreads();
  }
  if (t < NCHUNK) chunkSum[t] = part[t] - v;   // exclusive chunk base
  if (t == 255) off[N_NODES] = part[255];
}

__global__ __launch_bounds__(256) void scan3_kernel(const int* __restrict__ deg, const int* __restrict__ chunkSum,
                                                    int* __restrict__ off){
  __shared__ int part[256];
  int t = threadIdx.x;
  int i = blockIdx.x*256 + t;
  int v = (i < N_NODES) ? deg[i] : 0;
  part[t] = v;
  __syncthreads();
  for (int d=1; d<256; d<<=1){
    int x = (t>=d) ? part[t-d] : 0;
    __syncthreads();
    part[t] += x;
    __syncthreads();
  }
  if (i < N_NODES) off[i] = chunkSum[blockIdx.x] + part[t] - v;
}

// ---------------- CSR fill: LDS cursors, exact per-(block,segment) bases, no global atomics ----------------

__global__ __launch_bounds__(1024) void fillB_kernel(const int* __restrict__ row, const int* __restrict__ col,
                                                     const int* __restrict__ off, const ushort* __restrict__ C,
                                                     ushort* __restrict__ csrS){
  __shared__ uint cur[NBL];
  const int nb = blockIdx.x, s = blockIdx.y;
  const uint n0 = nb*NBL;
  const int t = threadIdx.x;
  #pragma unroll
  for (int k=0;k<NBL/1024;k++){
    int idx = k*1024 + t;
    int n = (int)n0 + idx;
    cur[idx] = (n < N_NODES) ? (uint)off[n] + C[(size_t)s*NPAD + n] : 0u;
  }
  __syncthreads();
  const uint4* cvv = (const uint4*)col;
  const uint4* rvv = (const uint4*)row;
  const int cb = s*CHUNKS_PER_SEG, ce = cb + CHUNKS_PER_SEG;
  for (int c = cb + t; c < ce; c += 1024){
    uint4 cv4 = cvv[c];
    uint4 rv4 = rvv[c];
    unsigned d0 = cv4.x - n0, d1 = cv4.y - n0, d2 = cv4.z - n0, d3 = cv4.w - n0;
    if (d0 < NBL){ uint p = atomicAdd(&cur[d0], 1u); csrS[p] = (ushort)rv4.x; }
    if (d1 < NBL){ uint p = atomicAdd(&cur[d1], 1u); csrS[p] = (ushort)rv4.y; }
    if (d2 < NBL){ uint p = atomicAdd(&cur[d2], 1u); csrS[p] = (ushort)rv4.z; }
    if (d3 < NBL){ uint p = atomicAdd(&cur[d3], 1u); csrS[p] = (ushort)rv4.w; }
  }
}

// ---------------- fp32 -> f16 conversions (row-major features) ----------------

__global__ __launch_bounds__(256) void cvt_x_kernel(const float* __restrict__ x, const float* __restrict__ dinv,
                                                    ushort* __restrict__ x16, ushort* __restrict__ xs16){
  int i = blockIdx.x*256 + threadIdx.x;   // 800000 chunks of 8 f16
  int node = i >> 4;
  float di = dinv[node];
  const float4* xin = (const float4*)x;
  float4 a = xin[(size_t)i*2], b = xin[(size_t)i*2+1];
  HU o, os;
  o.h[0]=(_Float16)a.x; o.h[1]=(_Float16)a.y; o.h[2]=(_Float16)a.z; o.h[3]=(_Float16)a.w;
  o.h[4]=(_Float16)b.x; o.h[5]=(_Float16)b.y; o.h[6]=(_Float16)b.z; o.h[7]=(_Float16)b.w;
  os.h[0]=(_Float16)(di*a.x); os.h[1]=(_Float16)(di*a.y); os.h[2]=(_Float16)(di*a.z); os.h[3]=(_Float16)(di*a.w);
  os.h[4]=(_Float16)(di*b.x); os.h[5]=(_Float16)(di*b.y); os.h[6]=(_Float16)(di*b.z); os.h[7]=(_Float16)(di*b.w);
  ((uint4*)x16)[i]  = o.u;
  ((uint4*)xs16)[i] = os.u;
}

__global__ __launch_bounds__(256) void cvt_w_kernel(const float* __restrict__ W1, const float* __restrict__ W2,
                                                    const float* __restrict__ W3, const float* __restrict__ Wf,
                                                    ushort* __restrict__ Wt){
  int m = blockIdx.x >> 2, q = blockIdx.x & 3;
  const float* src = (m < 4) ? (W1 + (size_t)m*16384)
                   : (m < 8) ? (W2 + (size_t)(m-4)*16384)
                   : (m < 12)? (W3 + (size_t)(m-8)*16384)
                   : Wf;
  ushort* dst = Wt + (size_t)m*16384;
  for (int it = threadIdx.x; it < 1024; it += 256){
    int idx = q*1024 + it;
    int n  = idx >> 5;
    int k4 = (idx & 31)*4;
    float v0 = src[(size_t)(k4+0)*D + n];
    float v1 = src[(size_t)(k4+1)*D + n];
    float v2 = src[(size_t)(k4+2)*D + n];
    float v3 = src[(size_t)(k4+3)*D + n];
    union { uint2 u; _Float16 h[4]; } o;
    o.h[0]=(_Float16)v0; o.h[1]=(_Float16)v1; o.h[2]=(_Float16)v2; o.h[3]=(_Float16)v3;
    *(uint2*)(dst + (size_t)n*D + k4) = o.u;
  }
}

// ---------------- SpMM, full-row gather, 16 outstanding loads/lane ----------------
// 16 lanes/node, uint4 (8 f16) per lane = full 256B source row per node-group.
// acc_i = sum_{j->i} sIn_j ; hOut_i = dinv_i*acc ; sOut_i = dinv_i^2*acc.

template<bool WS>
__global__ __launch_bounds__(256) void spmm16_kernel(const ushort* __restrict__ sIn, ushort* __restrict__ hOut,
                                                     ushort* __restrict__ sOut,
                                                     const int* __restrict__ off, const ushort* __restrict__ csrS,
                                                     const float* __restrict__ dinv){
  int g = blockIdx.x*256 + threadIdx.x;
  int node = g >> 4;
  if (node >= N_NODES) return;
  int c8 = (g & 15)*8;
  int b = off[node], e = off[node+1];
  float acc[8];
  #pragma unroll
  for (int k=0;k<8;k++) acc[k] = 0.f;
  int i = b;
  for (; i+16 <= e; i += 16){
    HU v[16];
    #pragma unroll
    for (int u=0;u<16;u++){
      int s = csrS[i+u];
      v[u].u = *(const uint4*)(sIn + (size_t)s*D + c8);
    }
    #pragma unroll
    for (int u=0;u<16;u++){
      #pragma unroll
      for (int k=0;k<8;k++) acc[k] += (float)v[u].h[k];
    }
  }
  for (; i+4 <= e; i += 4){
    HU v[4];
    #pragma unroll
    for (int u=0;u<4;u++){
      int s = csrS[i+u];
      v[u].u = *(const uint4*)(sIn + (size_t)s*D + c8);
    }
    #pragma unroll
    for (int u=0;u<4;u++){
      #pragma unroll
      for (int k=0;k<8;k++) acc[k] += (float)v[u].h[k];
    }
  }
  for (; i < e; i++){
    int s = csrS[i];
    HU v0; v0.u = *(const uint4*)(sIn + (size_t)s*D + c8);
    #pragma unroll
    for (int k=0;k<8;k++) acc[k] += (float)v0.h[k];
  }
  float di = dinv[node];
  HU oh;
  #pragma unroll
  for (int k=0;k<8;k++) oh.h[k] = (_Float16)(di*acc[k]);
  __builtin_nontemporal_store(oh.v, (u32x4*)(hOut + (size_t)node*D + c8));
  if (WS){
    HU os;
    #pragma unroll
    for (int k=0;k<8;k++) os.h[k] = (_Float16)(di*di*acc[k]);
    __builtin_nontemporal_store(os.v, (u32x4*)(sOut + (size_t)node*D + c8));
  }
}

// ---------------- fused layer GEMM via MFMA f16 (row-major) ----------------
// out = relu( sum_src S_src @ W_src + b ); optionally also sOut = dinv.*out.
// NOTE: out may alias s0 — each block reads exactly the rows it writes (staging), stores after.

template<int NSRC, bool RELU, bool OUTF32, bool WS>
__global__ __launch_bounds__(256) void gemm_mfma_kernel(const ushort* s0,
    const ushort* __restrict__ s1, const ushort* __restrict__ s2, const ushort* __restrict__ s3,
    const ushort* __restrict__ Wt, const float* __restrict__ bias, const float* __restrict__ dinv,
    void* outp, ushort* __restrict__ sOut){
  __shared__ ushort Xs[64*136];
  const int tid  = threadIdx.x;
  const int wave = tid >> 6, lane = tid & 63;
  const int quad = lane >> 4, l16 = lane & 15;
  const int wm = wave & 1, wn = wave >> 1;
  const int row0 = blockIdx.x * 64;

  f32x4 acc[2][4];
  #pragma unroll
  for (int i=0;i<2;i++)
    #pragma unroll
    for (int j=0;j<4;j++) acc[i][j] = (f32x4){0.f,0.f,0.f,0.f};

  #pragma unroll
  for (int src=0; src<NSRC; src++){
    const ushort* sp = (src==0)?s0:(src==1)?s1:(src==2)?s2:s3;
    __syncthreads();
    for (int i=tid; i<1024; i+=256){
      int r = i >> 4, c = i & 15;
      int gr = row0 + r;
      uint4 v = make_uint4(0u,0u,0u,0u);
      if (gr < N_NODES) v = *(const uint4*)(sp + (size_t)gr*D + c*8);
      *(uint4*)(&Xs[r*136 + c*8]) = v;
    }
    __syncthreads();
    const ushort* wsrc = Wt + (size_t)src*16384;
    #pragma unroll
    for (int ks=0; ks<4; ks++){
      f16x8 a0 = *(const f16x8*)(&Xs[(wm*32 +      l16)*136 + ks*32 + quad*8]);
      f16x8 a1 = *(const f16x8*)(&Xs[(wm*32 + 16 + l16)*136 + ks*32 + quad*8]);
      #pragma unroll
      for (int j=0;j<4;j++){
        f16x8 bfrag = *(const f16x8*)(wsrc + (size_t)(wn*64 + j*16 + l16)*D + ks*32 + quad*8);
        acc[0][j] = __builtin_amdgcn_mfma_f32_16x16x32_f16(a0, bfrag, acc[0][j], 0, 0, 0);
        acc[1][j] = __builtin_amdgcn_mfma_f32_16x16x32_f16(a1, bfrag, acc[1][j], 0, 0, 0);
      }
    }
  }
  #pragma unroll
  for (int j=0;j<4;j++){
    int colj = wn*64 + j*16 + l16;
    float bv = bias[colj];
    #pragma unroll
    for (int i=0;i<2;i++){
      int brow = row0 + wm*32 + i*16 + quad*4;
      #pragma unroll
      for (int r=0;r<4;r++){
        int grow = brow + r;
        if (grow < N_NODES){
          float v = acc[i][j][r] + bv;
          if (RELU) v = fmaxf(v, 0.f);
          if (OUTF32){
            ((float*)outp)[(size_t)grow*D + colj] = v;
          } else {
            ((ushort*)outp)[(size_t)grow*D + colj] = __builtin_bit_cast(ushort, (_Float16)v);
            if (WS) sOut[(size_t)grow*D + colj] = __builtin_bit_cast(ushort, (_Float16)(dinv[grow]*v));
          }
        }
      }
    }
  }
}

// ---------------- launch ----------------

extern "C" void kernel_launch(void* const* d_in, const int* in_sizes, int n_in,
                              void* d_out, int out_size, void* d_ws, size_t ws_size,
                              hipStream_t stream){
  const float* x  = (const float*)d_in[0];
  const int*   ei = (const int*)d_in[1];
  const float* W1 = (const float*)d_in[2];
  const float* b1 = (const float*)d_in[3];
  const float* W2 = (const float*)d_in[4];
  const float* b2 = (const float*)d_in[5];
  const float* W3 = (const float*)d_in[6];
  const float* b3 = (const float*)d_in[7];
  const float* Wf = (const float*)d_in[8];
  const float* bf = (const float*)d_in[9];
  float* out = (float*)d_out;

  const int* row = ei;            // edge_index[0]
  const int* col = ei + N_EDGES;  // edge_index[1]

  // workspace layout (~107 MB)
  char* w = (char*)d_ws;
  ushort* csrS = (ushort*)w;  w += (size_t)N_EDGES*2;
  ushort* x16  = (ushort*)w;  w += (size_t)N_NODES*D*2;
  ushort* xs16 = (ushort*)w;  w += (size_t)N_NODES*D*2;    // reused as Dh after hop-1 (dead then)
  ushort* Ah   = (ushort*)w;  w += (size_t)N_NODES*D*2;
  ushort* As   = (ushort*)w;  w += (size_t)N_NODES*D*2;
  ushort* Bh   = (ushort*)w;  w += (size_t)N_NODES*D*2;
  ushort* Bs   = (ushort*)w;  w += (size_t)N_NODES*D*2;
  ushort* Ch   = (ushort*)w;  w += (size_t)N_NODES*D*2;
  ushort* Cs   = (ushort*)w;  w += (size_t)N_NODES*D*2;
  ushort* Wt   = (ushort*)w;  w += (size_t)13*D*D*2;
  int* deg     = (int*)w;     w += (size_t)N_NODES*4;
  int* off     = (int*)w;     w += (size_t)(N_NODES+1)*4;
  int* chunkS  = (int*)w;     w += (size_t)256*4;
  float* dinv  = (float*)w;
  ushort* Dh = xs16;
  // Cc (16 MB = NSEG x NPAD ushort) aliases Ah+As: dead before gemm L1 writes Ah/As.
  ushort* Cc = Ah;

  const int GB = (N_NODES + 63)/64;   // 782
  const int SB = N_NODES*16/256;      // 3125 (exact)

  histA_kernel<<<dim3(NODEBLKS,NSEG),1024,0,stream>>>(col, Cc);
  segprefix_kernel<<<NCHUNK,256,0,stream>>>(Cc, deg, dinv);
  scan1_kernel<<<NCHUNK,256,0,stream>>>(deg, chunkS);
  scan2_kernel<<<1,256,0,stream>>>(chunkS, off);
  scan3_kernel<<<NCHUNK,256,0,stream>>>(deg, chunkS, off);
  fillB_kernel<<<dim3(NODEBLKS,NSEG),1024,0,stream>>>(row, col, off, Cc, csrS);
  cvt_x_kernel<<<3125,256,0,stream>>>(x, dinv, x16, xs16);
  cvt_w_kernel<<<52,256,0,stream>>>(W1, W2, W3, Wf, Wt);

  // layer 1
  spmm16_kernel<true ><<<SB,256,0,stream>>>(xs16, Bh, Bs, off, csrS, dinv);
  spmm16_kernel<true ><<<SB,256,0,stream>>>(Bs,   Ch, Cs, off, csrS, dinv);
  spmm16_kernel<false><<<SB,256,0,stream>>>(Cs,   Dh, nullptr, off, csrS, dinv);
  gemm_mfma_kernel<4,true,false,true><<<GB,256,0,stream>>>(x16, Bh, Ch, Dh, Wt+0*16384, b1, dinv, Ah, As);
  // layer 2 (gemm out aliases its s0 = Ah; safe)
  spmm16_kernel<true ><<<SB,256,0,stream>>>(As, Bh, Bs, off, csrS, dinv);
  spmm16_kernel<true ><<<SB,256,0,stream>>>(Bs, Ch, Cs, off, csrS, dinv);
  spmm16_kernel<false><<<SB,256,0,stream>>>(Cs, Dh, nullptr, off, csrS, dinv);
  gemm_mfma_kernel<4,true,false,true><<<GB,256,0,stream>>>(Ah, Bh, Ch, Dh, Wt+4*16384, b2, dinv, Ah, As);
  // layer 3
  spmm16_kernel<true ><<<SB,256,0,stream>>>(As, Bh, Bs, off, csrS, dinv);
  spmm16_kernel<true ><<<SB,256,0,stream>>>(Bs, Ch, Cs, off, csrS, dinv);
  spmm16_kernel<false><<<SB,256,0,stream>>>(Cs, Dh, nullptr, off, csrS, dinv);
  gemm_mfma_kernel<4,true,false,true><<<GB,256,0,stream>>>(Ah, Bh, Ch, Dh, Wt+8*16384, b3, dinv, Ah, As);
  // final head (fp32 out)
  gemm_mfma_kernel<1,false,true,false><<<GB,256,0,stream>>>(Ah, nullptr, nullptr, nullptr, Wt+12*16384, bf, dinv, out, nullptr);
}

// Round 10
// 723.483 us; speedup vs baseline: 1.3111x; 1.0304x over previous
//
#include <hip/hip_runtime.h>

#define N_NODES 50000
#define N_EDGES 1600000
#define D 128
#define NCHUNK 196            // ceil(N_NODES/256) for scans
#define NBL 16384             // nodes per hist/fill block (64KB LDS; 1024-thr blocks cap at 2/CU anyway)
#define NODEBLKS 4            // ceil(N_NODES/NBL)
#define NPAD 65536            // NODEBLKS*NBL
#define NSEG 128
#define CHUNKS_PER_SEG 3125   // uint4 chunks per segment (E/4/NSEG)

typedef _Float16 f16x8 __attribute__((ext_vector_type(8)));
typedef float f32x4 __attribute__((ext_vector_type(4)));
typedef uint u32x4 __attribute__((ext_vector_type(4)));   // ext-vector: valid for nontemporal builtins

union HU { uint4 u; u32x4 v; _Float16 h[8]; };

// ---------------- preprocessing: node-range-owning scan (NO global atomics) ----------------

__global__ __launch_bounds__(1024) void histA_kernel(const int* __restrict__ col, ushort* __restrict__ C){
  __shared__ uint cnt[NBL];
  const int nb = blockIdx.x, s = blockIdx.y;
  const uint n0 = nb*NBL;
  const int t = threadIdx.x;
  #pragma unroll
  for (int k=0;k<NBL/1024;k++) cnt[k*1024 + t] = 0;
  __syncthreads();
  const uint4* cv = (const uint4*)col;
  const int cb = s*CHUNKS_PER_SEG, ce = cb + CHUNKS_PER_SEG;
  for (int c = cb + t; c < ce; c += 1024){
    uint4 v = cv[c];
    unsigned d0 = v.x - n0, d1 = v.y - n0, d2 = v.z - n0, d3 = v.w - n0;
    if (d0 < NBL) atomicAdd(&cnt[d0], 1u);
    if (d1 < NBL) atomicAdd(&cnt[d1], 1u);
    if (d2 < NBL) atomicAdd(&cnt[d2], 1u);
    if (d3 < NBL) atomicAdd(&cnt[d3], 1u);
  }
  __syncthreads();
  #pragma unroll
  for (int k=0;k<NBL/1024;k++)
    C[(size_t)s*NPAD + n0 + k*1024 + t] = (ushort)cnt[k*1024 + t];
}

// In-place exclusive prefix of C along segments; deg, dinv, rdeg=sqrt(deg); fused scan1 (chunk sums).
__global__ __launch_bounds__(256) void segprefix_kernel(ushort* __restrict__ C, int* __restrict__ deg,
                                                        float* __restrict__ dinv, float* __restrict__ rdeg,
                                                        int* __restrict__ chunkSum){
  __shared__ int red[256];
  int t = threadIdx.x;
  int n = blockIdx.x*256 + t;
  uint run = 0;
  if (n < N_NODES){
    #pragma unroll
    for (int s=0;s<NSEG;s++){
      uint v = C[(size_t)s*NPAD + n];
      C[(size_t)s*NPAD + n] = (ushort)run;
      run += v;
    }
    deg[n] = (int)run;
    dinv[n] = (run > 0) ? rsqrtf((float)run) : 0.0f;
    rdeg[n] = sqrtf((float)run);
  }
  red[t] = (int)run;
  __syncthreads();
  for (int d=128; d>0; d>>=1){
    if (t < d) red[t] += red[t+d];
    __syncthreads();
  }
  if (t == 0) chunkSum[blockIdx.x] = red[0];
}

// ---------------- parallel exclusive scan over deg -> off (chunk sums from segprefix) ----------------

__global__ __launch_bounds__(256) void scan2_kernel(int* __restrict__ chunkSum, int* __restrict__ off){
  __shared__ int part[256];
  int t = threadIdx.x;
  int v = (t < NCHUNK) ? chunkSum[t] : 0;
  part[t] = v;
  __syncthreads();
  for (int d=1; d<256; d<<=1){
    int x = (t>=d) ? part[t-d] : 0;
    __syncthreads();
    part[t] += x;
    __syncthreads();
  }
  if (t < NCHUNK) chunkSum[t] = part[t] - v;   // exclusive chunk base
  if (t == 255) off[N_NODES] = part[255];
}

__global__ __launch_bounds__(256) void scan3_kernel(const int* __restrict__ deg, const int* __restrict__ chunkSum,
                                                    int* __restrict__ off){
  __shared__ int part[256];
  int t = threadIdx.x;
  int i = blockIdx.x*256 + t;
  int v = (i < N_NODES) ? deg[i] : 0;
  part[t] = v;
  __syncthreads();
  for (int d=1; d<256; d<<=1){
    int x = (t>=d) ? part[t-d] : 0;
    __syncthreads();
    part[t] += x;
    __syncthreads();
  }
  if (i < N_NODES) off[i] = chunkSum[blockIdx.x] + part[t] - v;
}

// ---------------- CSR fill: LDS cursors, exact per-(block,segment) bases, no global atomics ----------------

__global__ __launch_bounds__(1024) void fillB_kernel(const int* __restrict__ row, const int* __restrict__ col,
                                                     const int* __restrict__ off, const ushort* __restrict__ C,
                                                     ushort* __restrict__ csrS){
  __shared__ uint cur[NBL];
  const int nb = blockIdx.x, s = blockIdx.y;
  const uint n0 = nb*NBL;
  const int t = threadIdx.x;
  #pragma unroll
  for (int k=0;k<NBL/1024;k++){
    int idx = k*1024 + t;
    int n = (int)n0 + idx;
    cur[idx] = (n < N_NODES) ? (uint)off[n] + C[(size_t)s*NPAD + n] : 0u;
  }
  __syncthreads();
  const uint4* cvv = (const uint4*)col;
  const uint4* rvv = (const uint4*)row;
  const int cb = s*CHUNKS_PER_SEG, ce = cb + CHUNKS_PER_SEG;
  for (int c = cb + t; c < ce; c += 1024){
    uint4 cv4 = cvv[c];
    uint4 rv4 = rvv[c];
    unsigned d0 = cv4.x - n0, d1 = cv4.y - n0, d2 = cv4.z - n0, d3 = cv4.w - n0;
    if (d0 < NBL){ uint p = atomicAdd(&cur[d0], 1u); csrS[p] = (ushort)rv4.x; }
    if (d1 < NBL){ uint p = atomicAdd(&cur[d1], 1u); csrS[p] = (ushort)rv4.y; }
    if (d2 < NBL){ uint p = atomicAdd(&cur[d2], 1u); csrS[p] = (ushort)rv4.z; }
    if (d3 < NBL){ uint p = atomicAdd(&cur[d3], 1u); csrS[p] = (ushort)rv4.w; }
  }
}

// ---------------- fp32 -> f16 conversions ----------------
// x16 = f16(x) (h-form, layer-1 k=0 GEMM input); xs16 = f16(dinv*x) (s-form, hop-1 gather source).

__global__ __launch_bounds__(256) void cvt_x_kernel(const float* __restrict__ x, const float* __restrict__ dinv,
                                                    ushort* __restrict__ x16, ushort* __restrict__ xs16){
  int i = blockIdx.x*256 + threadIdx.x;   // 800000 chunks of 8 f16
  int node = i >> 4;
  float di = dinv[node];
  const float4* xin = (const float4*)x;
  float4 a = xin[(size_t)i*2], b = xin[(size_t)i*2+1];
  HU o, os;
  o.h[0]=(_Float16)a.x; o.h[1]=(_Float16)a.y; o.h[2]=(_Float16)a.z; o.h[3]=(_Float16)a.w;
  o.h[4]=(_Float16)b.x; o.h[5]=(_Float16)b.y; o.h[6]=(_Float16)b.z; o.h[7]=(_Float16)b.w;
  os.h[0]=(_Float16)(di*a.x); os.h[1]=(_Float16)(di*a.y); os.h[2]=(_Float16)(di*a.z); os.h[3]=(_Float16)(di*a.w);
  os.h[4]=(_Float16)(di*b.x); os.h[5]=(_Float16)(di*b.y); os.h[6]=(_Float16)(di*b.z); os.h[7]=(_Float16)(di*b.w);
  ((uint4*)x16)[i]  = o.u;
  ((uint4*)xs16)[i] = os.u;
}

__global__ __launch_bounds__(256) void cvt_w_kernel(const float* __restrict__ W1, const float* __restrict__ W2,
                                                    const float* __restrict__ W3, const float* __restrict__ Wf,
                                                    ushort* __restrict__ Wt){
  int m = blockIdx.x >> 2, q = blockIdx.x & 3;
  const float* src = (m < 4) ? (W1 + (size_t)m*16384)
                   : (m < 8) ? (W2 + (size_t)(m-4)*16384)
                   : (m < 12)? (W3 + (size_t)(m-8)*16384)
                   : Wf;
  ushort* dst = Wt + (size_t)m*16384;
  for (int it = threadIdx.x; it < 1024; it += 256){
    int idx = q*1024 + it;
    int n  = idx >> 5;
    int k4 = (idx & 31)*4;
    float v0 = src[(size_t)(k4+0)*D + n];
    float v1 = src[(size_t)(k4+1)*D + n];
    float v2 = src[(size_t)(k4+2)*D + n];
    float v3 = src[(size_t)(k4+3)*D + n];
    union { uint2 u; _Float16 h[4]; } o;
    o.h[0]=(_Float16)v0; o.h[1]=(_Float16)v1; o.h[2]=(_Float16)v2; o.h[3]=(_Float16)v3;
    *(uint2*)(dst + (size_t)n*D + k4) = o.u;
  }
}

// ---------------- SpMM, full-row gather, s-form output only ----------------
// 16 lanes/node, uint4 (8 f16)/lane. sOut_i = dinv_i^2 * sum_{j->i} sIn_j.
// GEMM reconstructs h_i = sOut_i * sqrt(deg_i) exactly (deg=0 => both 0).

__global__ __launch_bounds__(256) void spmm16_kernel(const ushort* __restrict__ sIn, ushort* __restrict__ sOut,
                                                     const int* __restrict__ off, const ushort* __restrict__ csrS,
                                                     const float* __restrict__ dinv){
  int g = blockIdx.x*256 + threadIdx.x;
  int node = g >> 4;
  if (node >= N_NODES) return;
  int c8 = (g & 15)*8;
  int b = off[node], e = off[node+1];
  float acc[8];
  #pragma unroll
  for (int k=0;k<8;k++) acc[k] = 0.f;
  int i = b;
  for (; i+16 <= e; i += 16){
    HU v[16];
    #pragma unroll
    for (int u=0;u<16;u++){
      int s = csrS[i+u];
      v[u].u = *(const uint4*)(sIn + (size_t)s*D + c8);
    }
    #pragma unroll
    for (int u=0;u<16;u++){
      #pragma unroll
      for (int k=0;k<8;k++) acc[k] += (float)v[u].h[k];
    }
  }
  for (; i+4 <= e; i += 4){
    HU v[4];
    #pragma unroll
    for (int u=0;u<4;u++){
      int s = csrS[i+u];
      v[u].u = *(const uint4*)(sIn + (size_t)s*D + c8);
    }
    #pragma unroll
    for (int u=0;u<4;u++){
      #pragma unroll
      for (int k=0;k<8;k++) acc[k] += (float)v[u].h[k];
    }
  }
  for (; i < e; i++){
    int s = csrS[i];
    HU v0; v0.u = *(const uint4*)(sIn + (size_t)s*D + c8);
    #pragma unroll
    for (int k=0;k<8;k++) acc[k] += (float)v0.h[k];
  }
  float d2 = dinv[node]*dinv[node];
  HU os;
  #pragma unroll
  for (int k=0;k<8;k++) os.h[k] = (_Float16)(d2*acc[k]);
  __builtin_nontemporal_store(os.v, (u32x4*)(sOut + (size_t)node*D + c8));
}

// ---------------- fused layer GEMM via MFMA f16 ----------------
// out = relu( h0 @ W0 + sum_{k=1..3} (s_k*sqrt(deg)) @ W_k + b ).
// HEAD=false: write Ah (h-form) + As (dinv.*h). HEAD=true: h-tile -> LDS -> second GEMM vs WtH, fp32 out.
// NOTE: out may alias s0 — each block reads exactly the rows it writes (staging), stores after.

template<bool HEAD>
__global__ __launch_bounds__(256) void gemm_mfma_kernel(const ushort* s0,
    const ushort* __restrict__ s1, const ushort* __restrict__ s2, const ushort* __restrict__ s3,
    const ushort* __restrict__ Wt, const float* __restrict__ bias,
    const ushort* __restrict__ WtH, const float* __restrict__ biasH,
    const float* __restrict__ rdeg, const float* __restrict__ dinv,
    ushort* __restrict__ Ah, ushort* __restrict__ As, float* __restrict__ outF){
  __shared__ ushort Xs[64*136];
  const int tid  = threadIdx.x;
  const int wave = tid >> 6, lane = tid & 63;
  const int quad = lane >> 4, l16 = lane & 15;
  const int wm = wave & 1, wn = wave >> 1;
  const int row0 = blockIdx.x * 64;

  f32x4 acc[2][4];
  #pragma unroll
  for (int i=0;i<2;i++)
    #pragma unroll
    for (int j=0;j<4;j++) acc[i][j] = (f32x4){0.f,0.f,0.f,0.f};

  #pragma unroll
  for (int src=0; src<4; src++){
    const ushort* sp = (src==0)?s0:(src==1)?s1:(src==2)?s2:s3;
    __syncthreads();
    for (int i=tid; i<1024; i+=256){
      int r = i >> 4, c = i & 15;
      int gr = row0 + r;
      uint4 vz = make_uint4(0u,0u,0u,0u);
      HU v; v.u = vz;
      if (gr < N_NODES){
        v.u = *(const uint4*)(sp + (size_t)gr*D + c*8);
        if (src > 0){   // s-form -> h-form: multiply row by sqrt(deg)
          float rd = rdeg[gr];
          #pragma unroll
          for (int k=0;k<8;k++) v.h[k] = (_Float16)((float)v.h[k]*rd);
        }
      }
      *(uint4*)(&Xs[r*136 + c*8]) = v.u;
    }
    __syncthreads();
    const ushort* wsrc = Wt + (size_t)src*16384;
    #pragma unroll
    for (int ks=0; ks<4; ks++){
      f16x8 a0 = *(const f16x8*)(&Xs[(wm*32 +      l16)*136 + ks*32 + quad*8]);
      f16x8 a1 = *(const f16x8*)(&Xs[(wm*32 + 16 + l16)*136 + ks*32 + quad*8]);
      #pragma unroll
      for (int j=0;j<4;j++){
        f16x8 bfrag = *(const f16x8*)(wsrc + (size_t)(wn*64 + j*16 + l16)*D + ks*32 + quad*8);
        acc[0][j] = __builtin_amdgcn_mfma_f32_16x16x32_f16(a0, bfrag, acc[0][j], 0, 0, 0);
        acc[1][j] = __builtin_amdgcn_mfma_f32_16x16x32_f16(a1, bfrag, acc[1][j], 0, 0, 0);
      }
    }
  }

  if (!HEAD){
    // epilogue: bias+relu, write Ah (h) + As (dinv.*h). C/D layout: col=l16, row=quad*4+reg.
    #pragma unroll
    for (int j=0;j<4;j++){
      int colj = wn*64 + j*16 + l16;
      float bv = bias[colj];
      #pragma unroll
      for (int i=0;i<2;i++){
        int brow = row0 + wm*32 + i*16 + quad*4;
        #pragma unroll
        for (int r=0;r<4;r++){
          int grow = brow + r;
          if (grow < N_NODES){
            float v = fmaxf(acc[i][j][r] + bv, 0.f);
            Ah[(size_t)grow*D + colj] = __builtin_bit_cast(ushort, (_Float16)v);
            As[(size_t)grow*D + colj] = __builtin_bit_cast(ushort, (_Float16)(dinv[grow]*v));
          }
        }
      }
    }
  } else {
    // layer-3 h-tile -> LDS (f16), then fused head GEMM vs WtH, fp32 out.
    __syncthreads();   // all waves done reading Xs
    #pragma unroll
    for (int j=0;j<4;j++){
      int colj = wn*64 + j*16 + l16;
      float bv = bias[colj];
      #pragma unroll
      for (int i=0;i<2;i++){
        int lrow = wm*32 + i*16 + quad*4;
        #pragma unroll
        for (int r=0;r<4;r++){
          float v = fmaxf(acc[i][j][r] + bv, 0.f);
          Xs[(lrow + r)*136 + colj] = __builtin_bit_cast(ushort, (_Float16)v);
        }
      }
    }
    __syncthreads();
    f32x4 acc2[2][4];
    #pragma unroll
    for (int i=0;i<2;i++)
      #pragma unroll
      for (int j=0;j<4;j++) acc2[i][j] = (f32x4){0.f,0.f,0.f,0.f};
    #pragma unroll
    for (int ks=0; ks<4; ks++){
      f16x8 a0 = *(const f16x8*)(&Xs[(wm*32 +      l16)*136 + ks*32 + quad*8]);
      f16x8 a1 = *(const f16x8*)(&Xs[(wm*32 + 16 + l16)*136 + ks*32 + quad*8]);
      #pragma unroll
      for (int j=0;j<4;j++){
        f16x8 bfrag = *(const f16x8*)(WtH + (size_t)(wn*64 + j*16 + l16)*D + ks*32 + quad*8);
        acc2[0][j] = __builtin_amdgcn_mfma_f32_16x16x32_f16(a0, bfrag, acc2[0][j], 0, 0, 0);
        acc2[1][j] = __builtin_amdgcn_mfma_f32_16x16x32_f16(a1, bfrag, acc2[1][j], 0, 0, 0);
      }
    }
    #pragma unroll
    for (int j=0;j<4;j++){
      int colj = wn*64 + j*16 + l16;
      float bv = biasH[colj];
      #pragma unroll
      for (int i=0;i<2;i++){
        int brow = row0 + wm*32 + i*16 + quad*4;
        #pragma unroll
        for (int r=0;r<4;r++){
          int grow = brow + r;
          if (grow < N_NODES)
            outF[(size_t)grow*D + colj] = acc2[i][j][r] + bv;
        }
      }
    }
  }
}

// ---------------- launch ----------------

extern "C" void kernel_launch(void* const* d_in, const int* in_sizes, int n_in,
                              void* d_out, int out_size, void* d_ws, size_t ws_size,
                              hipStream_t stream){
  const float* x  = (const float*)d_in[0];
  const int*   ei = (const int*)d_in[1];
  const float* W1 = (const float*)d_in[2];
  const float* b1 = (const float*)d_in[3];
  const float* W2 = (const float*)d_in[4];
  const float* b2 = (const float*)d_in[5];
  const float* W3 = (const float*)d_in[6];
  const float* b3 = (const float*)d_in[7];
  const float* Wf = (const float*)d_in[8];
  const float* bf = (const float*)d_in[9];
  float* out = (float*)d_out;

  const int* row = ei;            // edge_index[0]
  const int* col = ei + N_EDGES;  // edge_index[1]

  // workspace layout (~82 MB)
  char* w = (char*)d_ws;
  ushort* csrS = (ushort*)w;  w += (size_t)N_EDGES*2;
  ushort* x16  = (ushort*)w;  w += (size_t)N_NODES*D*2;
  ushort* xs16 = (ushort*)w;  w += (size_t)N_NODES*D*2;    // reused as Ds (hop-3 s) after hop-1 (dead then)
  ushort* Ah   = (ushort*)w;  w += (size_t)N_NODES*D*2;
  ushort* As   = (ushort*)w;  w += (size_t)N_NODES*D*2;
  ushort* Bs   = (ushort*)w;  w += (size_t)N_NODES*D*2;
  ushort* Cs   = (ushort*)w;  w += (size_t)N_NODES*D*2;
  ushort* Wt   = (ushort*)w;  w += (size_t)13*D*D*2;
  int* deg     = (int*)w;     w += (size_t)N_NODES*4;
  int* off     = (int*)w;     w += (size_t)(N_NODES+1)*4;
  int* chunkS  = (int*)w;     w += (size_t)256*4;
  float* dinv  = (float*)w;   w += (size_t)N_NODES*4;
  float* rdeg  = (float*)w;
  ushort* Ds = xs16;
  // Cc (16.8 MB = NSEG x NPAD ushort) aliases Ah+As: dead before gemm L1 writes Ah/As.
  ushort* Cc = Ah;

  const int GB = (N_NODES + 63)/64;   // 782
  const int SB = N_NODES*16/256;      // 3125 (exact)

  histA_kernel<<<dim3(NODEBLKS,NSEG),1024,0,stream>>>(col, Cc);
  segprefix_kernel<<<NCHUNK,256,0,stream>>>(Cc, deg, dinv, rdeg, chunkS);
  scan2_kernel<<<1,256,0,stream>>>(chunkS, off);
  scan3_kernel<<<NCHUNK,256,0,stream>>>(deg, chunkS, off);
  fillB_kernel<<<dim3(NODEBLKS,NSEG),1024,0,stream>>>(row, col, off, Cc, csrS);
  cvt_x_kernel<<<3125,256,0,stream>>>(x, dinv, x16, xs16);
  cvt_w_kernel<<<52,256,0,stream>>>(W1, W2, W3, Wf, Wt);

  // layer 1
  spmm16_kernel<<<SB,256,0,stream>>>(xs16, Bs, off, csrS, dinv);
  spmm16_kernel<<<SB,256,0,stream>>>(Bs,   Cs, off, csrS, dinv);
  spmm16_kernel<<<SB,256,0,stream>>>(Cs,   Ds, off, csrS, dinv);
  gemm_mfma_kernel<false><<<GB,256,0,stream>>>(x16, Bs, Cs, Ds, Wt+0*16384, b1, nullptr, nullptr, rdeg, dinv, Ah, As, nullptr);
  // layer 2 (gemm out aliases its s0 = Ah; safe)
  spmm16_kernel<<<SB,256,0,stream>>>(As, Bs, off, csrS, dinv);
  spmm16_kernel<<<SB,256,0,stream>>>(Bs, Cs, off, csrS, dinv);
  spmm16_kernel<<<SB,256,0,stream>>>(Cs, Ds, off, csrS, dinv);
  gemm_mfma_kernel<false><<<GB,256,0,stream>>>(Ah, Bs, Cs, Ds, Wt+4*16384, b2, nullptr, nullptr, rdeg, dinv, Ah, As, nullptr);
  // layer 3 + fused head (fp32 out)
  spmm16_kernel<<<SB,256,0,stream>>>(As, Bs, off, csrS, dinv);
  spmm16_kernel<<<SB,256,0,stream>>>(Bs, Cs, off, csrS, dinv);
  spmm16_kernel<<<SB,256,0,stream>>>(Cs, Ds, off, csrS, dinv);
  gemm_mfma_kernel<true ><<<GB,256,0,stream>>>(Ah, Bs, Cs, Ds, Wt+8*16384, b3, Wt+12*16384, bf, rdeg, dinv, nullptr, nullptr, out);
}